// Round 10
// baseline (199.903 us; speedup 1.0000x reference)
//
#include <hip/hip_runtime.h>
#include <hip/hip_bf16.h>
#include <cstddef>

// ---------------------------------------------------------------------------
// 2-layer GCN: h1 = x@W1; hmid = relu(Agg(h1) + b1); h2 = hmid@W2;
// out = Agg(h2) + b2.  Agg = sym-normalized scatter-add with self-loops.
// R1-R5: multi-block scan, bf16 h, 4B CSR, MFMA GEMMs, gemm2 fused into agg1.
// R7 (FAILED): intra-kernel producer/consumer spin sync ~130us. Kernel
//   boundaries are the cheap sync on this chip.
// R8: 6 launches, no dependent-phase spins. ~1.5us/launch measured.
// R9 (compile fix of R9 typo): wide gathers -- aggmm 16 lanes/edge x uint4
//   (1 VMEM/row, was 2), aggout 8 lanes/edge x uint4; count int4-vectorized;
//   fill blocks dispatched before gemm blocks.
// ---------------------------------------------------------------------------

typedef __attribute__((ext_vector_type(8))) short short8;
typedef __attribute__((ext_vector_type(4))) float f32x4;
typedef unsigned long long u64;

__device__ inline unsigned short f2bf(float f) {
    __hip_bfloat16 b = __float2bfloat16(f);
    return *reinterpret_cast<unsigned short*>(&b);
}
__device__ inline float bf2f_lo(unsigned int u) {
    unsigned int v = u << 16;
    return *reinterpret_cast<float*>(&v);
}
__device__ inline float bf2f_hi(unsigned int u) {
    unsigned int v = u & 0xffff0000u;
    return *reinterpret_cast<float*>(&v);
}
__device__ inline u64 ld_acq64(u64* p) {
    return __hip_atomic_load(p, __ATOMIC_ACQUIRE, __HIP_MEMORY_SCOPE_AGENT);
}
__device__ inline void st_rel64(u64* p, u64 v) {
    __hip_atomic_store(p, v, __ATOMIC_RELEASE, __HIP_MEMORY_SCOPE_AGENT);
}

// ---------------------------------------------------------------------------
// init: zero deg + lookback state; W1/W2 -> global MFMA-B fragment order.
// ---------------------------------------------------------------------------
__global__ __launch_bounds__(256) void init_kernel(const float* __restrict__ W1,
                                                   const float* __restrict__ W2,
                                                   unsigned short* __restrict__ W1f,
                                                   unsigned short* __restrict__ W2f,
                                                   int* __restrict__ deg,
                                                   u64* __restrict__ lb, int N) {
    int idx = blockIdx.x * 256 + threadIdx.x;
    if (idx < N) deg[idx] = 0;
    if (idx < 64) lb[idx] = 0;
    if (idx < 3072) {
        const float* W;
        unsigned short* Wf;
        int n, oct, Nc;
        if (idx < 2048) { W = W1; Wf = W1f; Nc = 128; n = idx >> 4; oct = idx & 15; }
        else { W = W2; Wf = W2f; Nc = 64; int i2 = idx - 2048; n = i2 >> 4; oct = i2 & 15; }
        int k0 = oct * 8;
        int ks = k0 >> 5, quad = (k0 >> 3) & 3, ntg = n >> 4;
        short8 v;
        #pragma unroll
        for (int j = 0; j < 8; j++) v[j] = (short)f2bf(W[(k0 + j) * Nc + n]);
        int off = (((ntg * 4 + ks) * 64) + (n & 15) + 16 * quad) * 8;
        *(short8*)(Wf + off) = v;
    }
}

// count: 4 edges per thread via int4 load
__global__ __launch_bounds__(256) void count_kernel(const int* __restrict__ dst, int E,
                                                    int* __restrict__ deg) {
    int i = (blockIdx.x * blockDim.x + threadIdx.x) * 4;
    if (i + 3 < E) {
        int4 d = *(const int4*)(dst + i);
        atomicAdd(&deg[d.x], 1);
        atomicAdd(&deg[d.y], 1);
        atomicAdd(&deg[d.z], 1);
        atomicAdd(&deg[d.w], 1);
    } else {
        for (; i < E; i++) atomicAdd(&deg[dst[i]], 1);
    }
}

// ---------------------------------------------------------------------------
// scan_lb: one-pass exclusive scan of deg via decoupled lookback (49 peer
// blocks, co-resident). Writes offs, cur, dinv.
// ---------------------------------------------------------------------------
__global__ __launch_bounds__(256) void scan_lb_kernel(const int* __restrict__ deg, int N,
                                                      u64* __restrict__ lb,
                                                      int* __restrict__ offs,
                                                      int* __restrict__ cur,
                                                      float* __restrict__ dinv) {
    __shared__ int ws[4];
    __shared__ int s_prefix;
    int tid = threadIdx.x;
    int sb = blockIdx.x;
    int SB = gridDim.x;
    int lane = tid & 63;
    int wv = tid >> 6;

    int i = sb * 1024 + tid * 4;
    int v0 = (i + 0 < N) ? deg[i + 0] : 0;
    int v1 = (i + 1 < N) ? deg[i + 1] : 0;
    int v2 = (i + 2 < N) ? deg[i + 2] : 0;
    int v3 = (i + 3 < N) ? deg[i + 3] : 0;
    int tsum = v0 + v1 + v2 + v3;
    int xs = tsum;
    #pragma unroll
    for (int off = 1; off < 64; off <<= 1) {
        int y = __shfl_up(xs, off, 64);
        if (lane >= off) xs += y;
    }
    if (lane == 63) ws[wv] = xs;
    __syncthreads();
    int wprefix = 0;
    #pragma unroll
    for (int w2 = 0; w2 < 4; w2++) wprefix += (w2 < wv) ? ws[w2] : 0;
    int chunk_total = ws[0] + ws[1] + ws[2] + ws[3];

    if (tid == 0) {
        st_rel64(&lb[sb], ((u64)(unsigned)chunk_total << 2) | 1ull);
        int prefix = 0;
        for (int pred = sb - 1; pred >= 0; --pred) {
            u64 v;
            do {
                v = ld_acq64(&lb[pred]);
                if ((v & 3) == 0) __builtin_amdgcn_s_sleep(1);
            } while ((v & 3) == 0);
            prefix += (int)(unsigned)(v >> 2);
            if ((v & 3) == 2) break;
        }
        st_rel64(&lb[sb], ((u64)(unsigned)(prefix + chunk_total) << 2) | 2ull);
        s_prefix = prefix;
    }
    __syncthreads();

    int carry = s_prefix;
    int e0 = carry + wprefix + xs - tsum;
    int e1 = e0 + v0, e2 = e1 + v1, e3 = e2 + v2;
    if (i + 0 < N) { offs[i + 0] = e0; cur[i + 0] = e0; dinv[i + 0] = rsqrtf((float)(v0 + 1)); }
    if (i + 1 < N) { offs[i + 1] = e1; cur[i + 1] = e1; dinv[i + 1] = rsqrtf((float)(v1 + 1)); }
    if (i + 2 < N) { offs[i + 2] = e2; cur[i + 2] = e2; dinv[i + 2] = rsqrtf((float)(v2 + 1)); }
    if (i + 3 < N) { offs[i + 3] = e3; cur[i + 3] = e3; dinv[i + 3] = rsqrtf((float)(v3 + 1)); }
    if (sb == SB - 1 && tid == 0) offs[N] = carry + chunk_total;
}

// ---------------------------------------------------------------------------
// fillgemm: blocks [0, FB) = CSR fill (longer pole, dispatched first);
//           blocks [FB, FB+GB) = gemm1. Independent -> no handshake.
// ---------------------------------------------------------------------------
__global__ __launch_bounds__(256) void fillgemm_kernel(
    const float* __restrict__ x, const unsigned short* __restrict__ W1f,
    unsigned short* __restrict__ h1, int N,
    const int* __restrict__ src, const int* __restrict__ dst, int E,
    int* __restrict__ cur, const float* __restrict__ dinv,
    unsigned int* __restrict__ csr) {

    const int FB = (E + 255) / 256;
    int b = blockIdx.x;
    int tid = threadIdx.x;

    __shared__ unsigned short As[64 * 128];  // 16 KB (gemm blocks only)

    if (b < FB) {
        // ---------------- fill ----------------
        int i = b * 256 + tid;
        if (i < E) {
            int s = src[i];
            int d = dst[i];
            int p = atomicAdd(&cur[d], 1);
            float w = dinv[s] * dinv[d];
            csr[p] = (unsigned int)s | ((unsigned int)f2bf(w) << 16);
        }
        return;
    }

    // ---------------- gemm1 ----------------
    constexpr int K = 128, BN = 128;
    int lane = tid & 63;
    int w = tid >> 6;
    int row0 = (b - FB) * 64;

    short8 bfr[2][4];
    #pragma unroll
    for (int nl = 0; nl < 2; nl++)
        #pragma unroll
        for (int ks = 0; ks < 4; ks++)
            bfr[nl][ks] = *(const short8*)(W1f + ((((w * 2 + nl) * 4 + ks) * 64) + lane) * 8);

    #pragma unroll
    for (int it = 0; it < 8; it++) {
        int idx = it * 256 + tid;
        int row = idx >> 5, kq = idx & 31;
        int k0 = kq * 4;
        int ks = k0 >> 5, quad = (k0 >> 3) & 3, j0 = k0 & 7, mt = row >> 4;
        ushort4 o = make_ushort4(0, 0, 0, 0);
        int gr = row0 + row;
        if (gr < N) {
            float4 a = *(const float4*)(x + (size_t)gr * K + k0);
            o.x = f2bf(a.x); o.y = f2bf(a.y); o.z = f2bf(a.z); o.w = f2bf(a.w);
        }
        int off = (((mt * 4 + ks) * 64) + (row & 15) + 16 * quad) * 8 + j0;
        *(ushort4*)(As + off) = o;
    }
    __syncthreads();

    f32x4 acc[4][2];
    #pragma unroll
    for (int mt = 0; mt < 4; mt++)
        #pragma unroll
        for (int nl = 0; nl < 2; nl++) acc[mt][nl] = (f32x4){0.f, 0.f, 0.f, 0.f};

    #pragma unroll
    for (int ks = 0; ks < 4; ks++) {
        short8 af[4];
        #pragma unroll
        for (int mt = 0; mt < 4; mt++)
            af[mt] = *(const short8*)(As + (((mt * 4 + ks) * 64) + lane) * 8);
        #pragma unroll
        for (int mt = 0; mt < 4; mt++)
            #pragma unroll
            for (int nl = 0; nl < 2; nl++)
                acc[mt][nl] = __builtin_amdgcn_mfma_f32_16x16x32_bf16(
                    af[mt], bfr[nl][ks], acc[mt][nl], 0, 0, 0);
    }

    int col16 = lane & 15;
    int rowq = lane >> 4;
    #pragma unroll
    for (int mt = 0; mt < 4; mt++) {
        #pragma unroll
        for (int nl = 0; nl < 2; nl++) {
            int gc = (w * 2 + nl) * 16 + col16;
            #pragma unroll
            for (int r = 0; r < 4; r++) {
                int gr = row0 + mt * 16 + rowq * 4 + r;
                if (gr < N) h1[(size_t)gr * BN + gc] = f2bf(acc[mt][nl][r]);
            }
        }
    }
}

// ---------------------------------------------------------------------------
// aggmm: fused Agg(layer1) + bias + ReLU + GEMM2 (h2 = hmid @ W2, bf16).
// Block = 4 waves = 16 nodes (4/wave sequential).
// Edge loop: 16 lanes/edge, uint4 (8 bf16/lane -> 256B row in ONE VMEM
// instr), 4 edges concurrent x unroll 2; reduce shfl_xor(16,32).
// Lane t4 owns k-octet [t4*8, t4*8+8) -> single short8 A-frag LDS store.
// ---------------------------------------------------------------------------
__global__ __launch_bounds__(256) void aggmm_kernel(const unsigned short* __restrict__ h1,
                                                    const int* __restrict__ offs,
                                                    const unsigned int* __restrict__ csr,
                                                    const float* __restrict__ dinv,
                                                    const float* __restrict__ b1,
                                                    const unsigned short* __restrict__ W2f,
                                                    unsigned short* __restrict__ h2,
                                                    int n) {
    __shared__ unsigned short As[4 * 64 * 8];  // 4 KB, one 16x128 A-tile

    int tid = threadIdx.x;
    int t = tid & 63;
    int w = tid >> 6;
    int p = t >> 4;      // edge slot (0..3)
    int t4 = t & 15;     // feature octet index (8 bf16)
    int nodebase = blockIdx.x * 16;

    short8 bw[4];
    #pragma unroll
    for (int ks = 0; ks < 4; ks++)
        bw[ks] = *(const short8*)(W2f + (((w * 4 + ks) * 64) + t) * 8);

    float4 biasA = *(const float4*)(b1 + t4 * 8);
    float4 biasB = *(const float4*)(b1 + t4 * 8 + 4);

    #pragma unroll
    for (int i = 0; i < 4; i++) {
        int row16 = w * 4 + i;
        int node = nodebase + row16;
        float a[8];
        #pragma unroll
        for (int v = 0; v < 8; v++) a[v] = 0.f;
        if (node < n) {
            float di = dinv[node];
            float sw = di * di;
            if (p == 0) {
                uint4 su = *(const uint4*)(h1 + (size_t)node * 128 + t4 * 8);
                a[0] = bf2f_lo(su.x) * sw; a[1] = bf2f_hi(su.x) * sw;
                a[2] = bf2f_lo(su.y) * sw; a[3] = bf2f_hi(su.y) * sw;
                a[4] = bf2f_lo(su.z) * sw; a[5] = bf2f_hi(su.z) * sw;
                a[6] = bf2f_lo(su.w) * sw; a[7] = bf2f_hi(su.w) * sw;
            }
            int e0 = offs[node];
            int e1 = offs[node + 1];
            int iters = (e1 - e0 + 7) >> 3;
            for (int it = 0; it < iters; it++) {
                int eb = e0 + it * 8;
                #pragma unroll
                for (int j = 0; j < 2; j++) {
                    int ee = eb + j * 4 + p;
                    int ec = min(ee, e1 - 1);
                    unsigned int pk = csr[ec];
                    float wgt = (ee < e1) ? bf2f_hi(pk) : 0.f;
                    int s = pk & 0xffff;
                    uint4 hu = *(const uint4*)(h1 + (size_t)s * 128 + t4 * 8);
                    a[0] += bf2f_lo(hu.x) * wgt; a[1] += bf2f_hi(hu.x) * wgt;
                    a[2] += bf2f_lo(hu.y) * wgt; a[3] += bf2f_hi(hu.y) * wgt;
                    a[4] += bf2f_lo(hu.z) * wgt; a[5] += bf2f_hi(hu.z) * wgt;
                    a[6] += bf2f_lo(hu.w) * wgt; a[7] += bf2f_hi(hu.w) * wgt;
                }
            }
        }
        #pragma unroll
        for (int v = 0; v < 8; v++) {
            a[v] += __shfl_xor(a[v], 16, 64);
            a[v] += __shfl_xor(a[v], 32, 64);
        }
        if (p == 0) {
            if (node < n) {
                a[0] = fmaxf(a[0] + biasA.x, 0.f);
                a[1] = fmaxf(a[1] + biasA.y, 0.f);
                a[2] = fmaxf(a[2] + biasA.z, 0.f);
                a[3] = fmaxf(a[3] + biasA.w, 0.f);
                a[4] = fmaxf(a[4] + biasB.x, 0.f);
                a[5] = fmaxf(a[5] + biasB.y, 0.f);
                a[6] = fmaxf(a[6] + biasB.z, 0.f);
                a[7] = fmaxf(a[7] + biasB.w, 0.f);
            }
            // k-octet k0 = t4*8: ks = t4>>2, quad = t4&3
            int ks = t4 >> 2, quad = t4 & 3;
            short8 pk8;
            #pragma unroll
            for (int v = 0; v < 8; v++) pk8[v] = (short)f2bf(a[v]);
            *(short8*)(As + ((ks * 64) + row16 + 16 * quad) * 8) = pk8;
        }
    }
    __syncthreads();

    f32x4 acc = (f32x4){0.f, 0.f, 0.f, 0.f};
    #pragma unroll
    for (int ks = 0; ks < 4; ks++) {
        short8 af = *(const short8*)(As + ((ks * 64) + t) * 8);
        acc = __builtin_amdgcn_mfma_f32_16x16x32_bf16(af, bw[ks], acc, 0, 0, 0);
    }

    int col = w * 16 + (t & 15);
    int rowq = t >> 4;
    #pragma unroll
    for (int r = 0; r < 4; r++) {
        int gr = nodebase + rowq * 4 + r;
        if (gr < n) h2[(size_t)gr * 64 + col] = f2bf(acc[r]);
    }
}

// ---------------------------------------------------------------------------
// aggout: Agg(layer2) + bias, fp32 out. One node/wave; 8 lanes/edge, uint4
// (128B row in one VMEM instr), 8 edges concurrent; shfl_xor(8,16,32).
// ---------------------------------------------------------------------------
__global__ __launch_bounds__(256) void aggout_kernel(const unsigned short* __restrict__ h2,
                                                     const int* __restrict__ offs,
                                                     const unsigned int* __restrict__ csr,
                                                     const float* __restrict__ dinv,
                                                     const float* __restrict__ b2,
                                                     float* __restrict__ out, int n) {
    int tid = threadIdx.x;
    int t = tid & 63;
    int w = tid >> 6;
    int node = blockIdx.x * 4 + w;
    if (node >= n) return;
    int p = t >> 3;      // edge slot (0..7)
    int t3 = t & 7;      // feature octet index

    float a[8];
    #pragma unroll
    for (int v = 0; v < 8; v++) a[v] = 0.f;
    float di = dinv[node];
    float sw = di * di;
    if (p == 0) {
        uint4 su = *(const uint4*)(h2 + (size_t)node * 64 + t3 * 8);
        a[0] = bf2f_lo(su.x) * sw; a[1] = bf2f_hi(su.x) * sw;
        a[2] = bf2f_lo(su.y) * sw; a[3] = bf2f_hi(su.y) * sw;
        a[4] = bf2f_lo(su.z) * sw; a[5] = bf2f_hi(su.z) * sw;
        a[6] = bf2f_lo(su.w) * sw; a[7] = bf2f_hi(su.w) * sw;
    }

    int e0 = offs[node];
    int e1 = offs[node + 1];
    int iters = (e1 - e0 + 7) >> 3;
    for (int it = 0; it < iters; it++) {
        int ee = e0 + it * 8 + p;
        int ec = min(ee, e1 - 1);
        unsigned int pk = csr[ec];
        float wgt = (ee < e1) ? bf2f_hi(pk) : 0.f;
        int s = pk & 0xffff;
        uint4 hu = *(const uint4*)(h2 + (size_t)s * 64 + t3 * 8);
        a[0] += bf2f_lo(hu.x) * wgt; a[1] += bf2f_hi(hu.x) * wgt;
        a[2] += bf2f_lo(hu.y) * wgt; a[3] += bf2f_hi(hu.y) * wgt;
        a[4] += bf2f_lo(hu.z) * wgt; a[5] += bf2f_hi(hu.z) * wgt;
        a[6] += bf2f_lo(hu.w) * wgt; a[7] += bf2f_hi(hu.w) * wgt;
    }
    #pragma unroll
    for (int v = 0; v < 8; v++) {
        a[v] += __shfl_xor(a[v], 8, 64);
        a[v] += __shfl_xor(a[v], 16, 64);
        a[v] += __shfl_xor(a[v], 32, 64);
    }
    if (p == 0) {
        float4 bA = *(const float4*)(b2 + t3 * 8);
        float4 bB = *(const float4*)(b2 + t3 * 8 + 4);
        float* op = out + (size_t)node * 64 + t3 * 8;
        *(float4*)op = make_float4(a[0] + bA.x, a[1] + bA.y, a[2] + bA.z, a[3] + bA.w);
        *(float4*)(op + 4) = make_float4(a[4] + bB.x, a[5] + bB.y, a[6] + bB.z, a[7] + bB.w);
    }
}

extern "C" void kernel_launch(void* const* d_in, const int* in_sizes, int n_in,
                              void* d_out, int out_size, void* d_ws, size_t ws_size,
                              hipStream_t stream) {
    const float* x  = (const float*)d_in[0];
    const int*   ei = (const int*)d_in[1];
    const float* W1 = (const float*)d_in[2];
    const float* b1 = (const float*)d_in[3];
    const float* W2 = (const float*)d_in[4];
    const float* b2 = (const float*)d_in[5];

    const int N = in_sizes[0] / 128;   // 50000
    const int E = in_sizes[1] / 2;     // 500000
    const int* src = ei;
    const int* dst = ei + E;

    char* p = (char*)d_ws;
    auto alloc = [&](size_t bytes) {
        char* r = p;
        p += (bytes + 255) & ~(size_t)255;
        return r;
    };
    int*   degi  = (int*)  alloc((size_t)N * 4);
    float* dinv  = (float*)alloc((size_t)N * 4);
    int*   offs  = (int*)  alloc((size_t)(N + 1) * 4);
    int*   cur   = (int*)  alloc((size_t)N * 4);
    u64*   lb    = (u64*)  alloc((size_t)64 * 8);
    unsigned int*   csr  = (unsigned int*)alloc((size_t)E * 4);
    unsigned short* W1f  = (unsigned short*)alloc((size_t)128 * 128 * 2);
    unsigned short* W2f  = (unsigned short*)alloc((size_t)64 * 128 * 2);
    unsigned short* h1   = (unsigned short*)alloc((size_t)N * 128 * 2);
    unsigned short* h2   = (unsigned short*)alloc((size_t)N * 64 * 2);
    float* out = (float*)d_out;

    const int GB = (N + 63) / 64;        // 782
    const int FB = (E + 255) / 256;      // 1954
    const int SB = (N + 1023) / 1024;    // 49
    const int CB = (E / 4 + 255) / 256;  // 489

    init_kernel<<<(N + 255) / 256, 256, 0, stream>>>(W1, W2, W1f, W2f, degi, lb, N);
    count_kernel<<<CB, 256, 0, stream>>>(dst, E, degi);
    scan_lb_kernel<<<SB, 256, 0, stream>>>(degi, N, lb, offs, cur, dinv);
    fillgemm_kernel<<<FB + GB, 256, 0, stream>>>(x, W1f, h1, N, src, dst, E,
                                                 cur, dinv, csr);
    aggmm_kernel<<<(N + 15) / 16, 256, 0, stream>>>(h1, offs, csr, dinv, b1, W2f, h2, N);
    aggout_kernel<<<(N + 3) / 4, 256, 0, stream>>>(h2, offs, csr, dinv, b2, out, N);
}

// Round 11
// 195.004 us; speedup vs baseline: 1.0251x; 1.0251x over previous
//
#include <hip/hip_runtime.h>
#include <hip/hip_bf16.h>
#include <cstddef>

// ---------------------------------------------------------------------------
// 2-layer GCN: h1 = x@W1; hmid = relu(Agg(h1) + b1); h2 = hmid@W2;
// out = Agg(h2) + b2.  Agg = sym-normalized scatter-add with self-loops.
// R1-R5: multi-block scan, bf16 h, MFMA GEMMs, gemm2 fused into agg1.
// R7 (FAILED): intra-kernel spin sync ~130us -> kernel boundaries are cheap.
// R8: 6 launches; aggmm 32 lanes/edge x uint2, aggout 16 lanes/edge x uint2
//   = local optimum for gather geometry (R6 narrower and R10 wider both lose).
// R11 (this): revert aggs to R8 geometry + NORMALIZATION FACTORING:
//   norm(s,d)=dinv[s]*dinv[d] -> fold dinv[s] into producer rows
//   (gemm1/aggmm epilogues scale by dinv[row]); edge loop is a pure row-sum;
//   CSR = bare ushort src (2 B/edge); fill loses 2 random dinv gathers/edge.
// ---------------------------------------------------------------------------

typedef __attribute__((ext_vector_type(8))) short short8;
typedef __attribute__((ext_vector_type(4))) float f32x4;
typedef unsigned long long u64;

__device__ inline unsigned short f2bf(float f) {
    __hip_bfloat16 b = __float2bfloat16(f);
    return *reinterpret_cast<unsigned short*>(&b);
}
__device__ inline float bf2f_lo(unsigned int u) {
    unsigned int v = u << 16;
    return *reinterpret_cast<float*>(&v);
}
__device__ inline float bf2f_hi(unsigned int u) {
    unsigned int v = u & 0xffff0000u;
    return *reinterpret_cast<float*>(&v);
}
__device__ inline u64 ld_acq64(u64* p) {
    return __hip_atomic_load(p, __ATOMIC_ACQUIRE, __HIP_MEMORY_SCOPE_AGENT);
}
__device__ inline void st_rel64(u64* p, u64 v) {
    __hip_atomic_store(p, v, __ATOMIC_RELEASE, __HIP_MEMORY_SCOPE_AGENT);
}

// ---------------------------------------------------------------------------
// init: zero deg + lookback state; W1/W2 -> global MFMA-B fragment order.
// ---------------------------------------------------------------------------
__global__ __launch_bounds__(256) void init_kernel(const float* __restrict__ W1,
                                                   const float* __restrict__ W2,
                                                   unsigned short* __restrict__ W1f,
                                                   unsigned short* __restrict__ W2f,
                                                   int* __restrict__ deg,
                                                   u64* __restrict__ lb, int N) {
    int idx = blockIdx.x * 256 + threadIdx.x;
    if (idx < N) deg[idx] = 0;
    if (idx < 64) lb[idx] = 0;
    if (idx < 3072) {
        const float* W;
        unsigned short* Wf;
        int n, oct, Nc;
        if (idx < 2048) { W = W1; Wf = W1f; Nc = 128; n = idx >> 4; oct = idx & 15; }
        else { W = W2; Wf = W2f; Nc = 64; int i2 = idx - 2048; n = i2 >> 4; oct = i2 & 15; }
        int k0 = oct * 8;
        int ks = k0 >> 5, quad = (k0 >> 3) & 3, ntg = n >> 4;
        short8 v;
        #pragma unroll
        for (int j = 0; j < 8; j++) v[j] = (short)f2bf(W[(k0 + j) * Nc + n]);
        int off = (((ntg * 4 + ks) * 64) + (n & 15) + 16 * quad) * 8;
        *(short8*)(Wf + off) = v;
    }
}

// count: 4 edges per thread via int4 load
__global__ __launch_bounds__(256) void count_kernel(const int* __restrict__ dst, int E,
                                                    int* __restrict__ deg) {
    int i = (blockIdx.x * blockDim.x + threadIdx.x) * 4;
    if (i + 3 < E) {
        int4 d = *(const int4*)(dst + i);
        atomicAdd(&deg[d.x], 1);
        atomicAdd(&deg[d.y], 1);
        atomicAdd(&deg[d.z], 1);
        atomicAdd(&deg[d.w], 1);
    } else {
        for (; i < E; i++) atomicAdd(&deg[dst[i]], 1);
    }
}

// ---------------------------------------------------------------------------
// scan_lb: one-pass exclusive scan of deg via decoupled lookback (49 peer
// blocks, co-resident). Writes offs, cur, dinv.
// ---------------------------------------------------------------------------
__global__ __launch_bounds__(256) void scan_lb_kernel(const int* __restrict__ deg, int N,
                                                      u64* __restrict__ lb,
                                                      int* __restrict__ offs,
                                                      int* __restrict__ cur,
                                                      float* __restrict__ dinv) {
    __shared__ int ws[4];
    __shared__ int s_prefix;
    int tid = threadIdx.x;
    int sb = blockIdx.x;
    int SB = gridDim.x;
    int lane = tid & 63;
    int wv = tid >> 6;

    int i = sb * 1024 + tid * 4;
    int v0 = (i + 0 < N) ? deg[i + 0] : 0;
    int v1 = (i + 1 < N) ? deg[i + 1] : 0;
    int v2 = (i + 2 < N) ? deg[i + 2] : 0;
    int v3 = (i + 3 < N) ? deg[i + 3] : 0;
    int tsum = v0 + v1 + v2 + v3;
    int xs = tsum;
    #pragma unroll
    for (int off = 1; off < 64; off <<= 1) {
        int y = __shfl_up(xs, off, 64);
        if (lane >= off) xs += y;
    }
    if (lane == 63) ws[wv] = xs;
    __syncthreads();
    int wprefix = 0;
    #pragma unroll
    for (int w2 = 0; w2 < 4; w2++) wprefix += (w2 < wv) ? ws[w2] : 0;
    int chunk_total = ws[0] + ws[1] + ws[2] + ws[3];

    if (tid == 0) {
        st_rel64(&lb[sb], ((u64)(unsigned)chunk_total << 2) | 1ull);
        int prefix = 0;
        for (int pred = sb - 1; pred >= 0; --pred) {
            u64 v;
            do {
                v = ld_acq64(&lb[pred]);
                if ((v & 3) == 0) __builtin_amdgcn_s_sleep(1);
            } while ((v & 3) == 0);
            prefix += (int)(unsigned)(v >> 2);
            if ((v & 3) == 2) break;
        }
        st_rel64(&lb[sb], ((u64)(unsigned)(prefix + chunk_total) << 2) | 2ull);
        s_prefix = prefix;
    }
    __syncthreads();

    int carry = s_prefix;
    int e0 = carry + wprefix + xs - tsum;
    int e1 = e0 + v0, e2 = e1 + v1, e3 = e2 + v2;
    if (i + 0 < N) { offs[i + 0] = e0; cur[i + 0] = e0; dinv[i + 0] = rsqrtf((float)(v0 + 1)); }
    if (i + 1 < N) { offs[i + 1] = e1; cur[i + 1] = e1; dinv[i + 1] = rsqrtf((float)(v1 + 1)); }
    if (i + 2 < N) { offs[i + 2] = e2; cur[i + 2] = e2; dinv[i + 2] = rsqrtf((float)(v2 + 1)); }
    if (i + 3 < N) { offs[i + 3] = e3; cur[i + 3] = e3; dinv[i + 3] = rsqrtf((float)(v3 + 1)); }
    if (sb == SB - 1 && tid == 0) offs[N] = carry + chunk_total;
}

// ---------------------------------------------------------------------------
// fillgemm: blocks [0, FB) = CSR fill (2 B/edge, no dinv reads);
//           blocks [FB, FB+GB) = gemm1 with dinv-scaled epilogue.
// Independent -> no handshake.
// ---------------------------------------------------------------------------
__global__ __launch_bounds__(256) void fillgemm_kernel(
    const float* __restrict__ x, const unsigned short* __restrict__ W1f,
    unsigned short* __restrict__ h1, int N,
    const int* __restrict__ src, const int* __restrict__ dst, int E,
    int* __restrict__ cur, const float* __restrict__ dinv,
    unsigned short* __restrict__ csr) {

    const int FB = (E + 255) / 256;
    int b = blockIdx.x;
    int tid = threadIdx.x;

    __shared__ unsigned short As[64 * 128];  // 16 KB (gemm blocks only)
    __shared__ float sdinv[64];

    if (b < FB) {
        // ---------------- fill ----------------
        int i = b * 256 + tid;
        if (i < E) {
            int s = src[i];
            int d = dst[i];
            int p = atomicAdd(&cur[d], 1);
            csr[p] = (unsigned short)s;
        }
        return;
    }

    // ---------------- gemm1: h1 = dinv . (x @ W1) ----------------
    constexpr int K = 128, BN = 128;
    int lane = tid & 63;
    int w = tid >> 6;
    int row0 = (b - FB) * 64;

    if (tid < 64) {
        int gr = row0 + tid;
        sdinv[tid] = (gr < N) ? dinv[gr] : 0.f;
    }

    short8 bfr[2][4];
    #pragma unroll
    for (int nl = 0; nl < 2; nl++)
        #pragma unroll
        for (int ks = 0; ks < 4; ks++)
            bfr[nl][ks] = *(const short8*)(W1f + ((((w * 2 + nl) * 4 + ks) * 64) + lane) * 8);

    #pragma unroll
    for (int it = 0; it < 8; it++) {
        int idx = it * 256 + tid;
        int row = idx >> 5, kq = idx & 31;
        int k0 = kq * 4;
        int ks = k0 >> 5, quad = (k0 >> 3) & 3, j0 = k0 & 7, mt = row >> 4;
        ushort4 o = make_ushort4(0, 0, 0, 0);
        int gr = row0 + row;
        if (gr < N) {
            float4 a = *(const float4*)(x + (size_t)gr * K + k0);
            o.x = f2bf(a.x); o.y = f2bf(a.y); o.z = f2bf(a.z); o.w = f2bf(a.w);
        }
        int off = (((mt * 4 + ks) * 64) + (row & 15) + 16 * quad) * 8 + j0;
        *(ushort4*)(As + off) = o;
    }
    __syncthreads();

    f32x4 acc[4][2];
    #pragma unroll
    for (int mt = 0; mt < 4; mt++)
        #pragma unroll
        for (int nl = 0; nl < 2; nl++) acc[mt][nl] = (f32x4){0.f, 0.f, 0.f, 0.f};

    #pragma unroll
    for (int ks = 0; ks < 4; ks++) {
        short8 af[4];
        #pragma unroll
        for (int mt = 0; mt < 4; mt++)
            af[mt] = *(const short8*)(As + (((mt * 4 + ks) * 64) + lane) * 8);
        #pragma unroll
        for (int mt = 0; mt < 4; mt++)
            #pragma unroll
            for (int nl = 0; nl < 2; nl++)
                acc[mt][nl] = __builtin_amdgcn_mfma_f32_16x16x32_bf16(
                    af[mt], bfr[nl][ks], acc[mt][nl], 0, 0, 0);
    }

    int col16 = lane & 15;
    int rowq = lane >> 4;
    #pragma unroll
    for (int mt = 0; mt < 4; mt++) {
        #pragma unroll
        for (int nl = 0; nl < 2; nl++) {
            int gc = (w * 2 + nl) * 16 + col16;
            #pragma unroll
            for (int r = 0; r < 4; r++) {
                int lr = mt * 16 + rowq * 4 + r;
                int gr = row0 + lr;
                if (gr < N) C_STORE: h1[(size_t)gr * BN + gc] = f2bf(acc[mt][nl][r] * sdinv[lr]);
            }
        }
    }
}

// ---------------------------------------------------------------------------
// aggmm: fused Agg(layer1) + bias + ReLU + GEMM2, epilogue-scaled by dinv.
// hmid[d] = relu(dinv[d]*(h1'[d] + sum_e h1'[src]) + b1); h2' = dinv . (hmid@W2)
// Block = 4 waves = 16 nodes (4/wave sequential). 32 lanes/edge (uint2 =
// 4 bf16), 2 edge slots x unroll 4 (8 edges/iter); reduce shfl_xor(32).
// ---------------------------------------------------------------------------
__global__ __launch_bounds__(256) void aggmm_kernel(const unsigned short* __restrict__ h1,
                                                    const int* __restrict__ offs,
                                                    const unsigned short* __restrict__ csr,
                                                    const float* __restrict__ dinv,
                                                    const float* __restrict__ b1,
                                                    const unsigned short* __restrict__ W2f,
                                                    unsigned short* __restrict__ h2,
                                                    int n) {
    __shared__ unsigned short As[4 * 64 * 8];  // 4 KB, one 16x128 A-tile

    int tid = threadIdx.x;
    int t = tid & 63;
    int w = tid >> 6;
    int p = t >> 5;      // edge slot (0/1)
    int t5 = t & 31;     // feature quad index (4 bf16)
    int nodebase = blockIdx.x * 16;

    short8 bw[4];
    #pragma unroll
    for (int ks = 0; ks < 4; ks++)
        bw[ks] = *(const short8*)(W2f + (((w * 4 + ks) * 64) + t) * 8);

    float4 bias = *(const float4*)(b1 + t5 * 4);

    #pragma unroll
    for (int i = 0; i < 4; i++) {
        int row16 = w * 4 + i;
        int node = nodebase + row16;
        float a0 = 0.f, a1 = 0.f, a2 = 0.f, a3 = 0.f;
        float di = 0.f;
        if (node < n) {
            di = dinv[node];
            if (p == 0) {
                uint2 su = *(const uint2*)(h1 + (size_t)node * 128 + t5 * 4);
                a0 = bf2f_lo(su.x); a1 = bf2f_hi(su.x);
                a2 = bf2f_lo(su.y); a3 = bf2f_hi(su.y);
            }
            int e0 = offs[node];
            int e1 = offs[node + 1];
            int iters = (e1 - e0 + 7) >> 3;
            for (int it = 0; it < iters; it++) {
                int eb = e0 + it * 8;
                #pragma unroll
                for (int j = 0; j < 4; j++) {
                    int ee = eb + j * 2 + p;
                    int ec = min(ee, e1 - 1);
                    int s = csr[ec];
                    float wgt = (ee < e1) ? 1.f : 0.f;
                    uint2 hu = *(const uint2*)(h1 + (size_t)s * 128 + t5 * 4);
                    a0 += bf2f_lo(hu.x) * wgt; a1 += bf2f_hi(hu.x) * wgt;
                    a2 += bf2f_lo(hu.y) * wgt; a3 += bf2f_hi(hu.y) * wgt;
                }
            }
        }
        a0 += __shfl_xor(a0, 32, 64);
        a1 += __shfl_xor(a1, 32, 64);
        a2 += __shfl_xor(a2, 32, 64);
        a3 += __shfl_xor(a3, 32, 64);
        if (p == 0) {
            if (node < n) {
                a0 = fmaxf(a0 * di + bias.x, 0.f);
                a1 = fmaxf(a1 * di + bias.y, 0.f);
                a2 = fmaxf(a2 * di + bias.z, 0.f);
                a3 = fmaxf(a3 * di + bias.w, 0.f);
            }
            int k0 = t5 * 4;
            int ks = k0 >> 5, quad = (k0 >> 3) & 3, j0 = k0 & 7;
            ushort4 pk4 = make_ushort4(f2bf(a0), f2bf(a1), f2bf(a2), f2bf(a3));
            *(ushort4*)(As + ((ks * 64) + row16 + 16 * quad) * 8 + j0) = pk4;
        }
    }
    __syncthreads();

    f32x4 acc = (f32x4){0.f, 0.f, 0.f, 0.f};
    #pragma unroll
    for (int ks = 0; ks < 4; ks++) {
        short8 af = *(const short8*)(As + ((ks * 64) + t) * 8);
        acc = __builtin_amdgcn_mfma_f32_16x16x32_bf16(af, bw[ks], acc, 0, 0, 0);
    }

    int col = w * 16 + (t & 15);
    int rowq = t >> 4;
    #pragma unroll
    for (int r = 0; r < 4; r++) {
        int gr = nodebase + rowq * 4 + r;
        if (gr < n) h2[(size_t)gr * 64 + col] = f2bf(acc[r] * dinv[gr]);
    }
}

// ---------------------------------------------------------------------------
// aggout: out[d] = dinv[d]*(h2'[d] + sum_e h2'[src]) + b2, fp32 out.
// One node/wave; 16 lanes/edge (uint2 = 4 bf16), 4 edge slots x unroll 2
// (8 edges/iter); reduce shfl_xor(16,32); float4 epilogue.
// ---------------------------------------------------------------------------
__global__ __launch_bounds__(256) void aggout_kernel(const unsigned short* __restrict__ h2,
                                                     const int* __restrict__ offs,
                                                     const unsigned short* __restrict__ csr,
                                                     const float* __restrict__ dinv,
                                                     const float* __restrict__ b2,
                                                     float* __restrict__ out, int n) {
    int tid = threadIdx.x;
    int t = tid & 63;
    int w = tid >> 6;
    int node = blockIdx.x * 4 + w;
    if (node >= n) return;
    int p = t >> 4;      // edge slot (0..3)
    int t4 = t & 15;     // feature quad index

    float a0 = 0.f, a1 = 0.f, a2 = 0.f, a3 = 0.f;
    float di = dinv[node];
    if (p == 0) {
        uint2 su = *(const uint2*)(h2 + (size_t)node * 64 + t4 * 4);
        a0 = bf2f_lo(su.x); a1 = bf2f_hi(su.x);
        a2 = bf2f_lo(su.y); a3 = bf2f_hi(su.y);
    }

    int e0 = offs[node];
    int e1 = offs[node + 1];
    int iters = (e1 - e0 + 7) >> 3;
    for (int it = 0; it < iters; it++) {
        int eb = e0 + it * 8;
        #pragma unroll
        for (int j = 0; j < 2; j++) {
            int ee = eb + j * 4 + p;
            int ec = min(ee, e1 - 1);
            int s = csr[ec];
            float wgt = (ee < e1) ? 1.f : 0.f;
            uint2 hu = *(const uint2*)(h2 + (size_t)s * 64 + t4 * 4);
            a0 += bf2f_lo(hu.x) * wgt; a1 += bf2f_hi(hu.x) * wgt;
            a2 += bf2f_lo(hu.y) * wgt; a3 += bf2f_hi(hu.y) * wgt;
        }
    }
    a0 += __shfl_xor(a0, 16, 64); a1 += __shfl_xor(a1, 16, 64);
    a2 += __shfl_xor(a2, 16, 64); a3 += __shfl_xor(a3, 16, 64);
    a0 += __shfl_xor(a0, 32, 64); a1 += __shfl_xor(a1, 32, 64);
    a2 += __shfl_xor(a2, 32, 64); a3 += __shfl_xor(a3, 32, 64);
    if (p == 0) {
        float4 bb = *(const float4*)(b2 + t4 * 4);
        *(float4*)(out + (size_t)node * 64 + t4 * 4) =
            make_float4(a0 * di + bb.x, a1 * di + bb.y, a2 * di + bb.z, a3 * di + bb.w);
    }
}

extern "C" void kernel_launch(void* const* d_in, const int* in_sizes, int n_in,
                              void* d_out, int out_size, void* d_ws, size_t ws_size,
                              hipStream_t stream) {
    const float* x  = (const float*)d_in[0];
    const int*   ei = (const int*)d_in[1];
    const float* W1 = (const float*)d_in[2];
    const float* b1 = (const float*)d_in[3];
    const float* W2 = (const float*)d_in[4];
    const float* b2 = (const float*)d_in[5];

    const int N = in_sizes[0] / 128;   // 50000
    const int E = in_sizes[1] / 2;     // 500000
    const int* src = ei;
    const int* dst = ei + E;

    char* p = (char*)d_ws;
    auto alloc = [&](size_t bytes) {
        char* r = p;
        p += (bytes + 255) & ~(size_t)255;
        return r;
    };
    int*   degi  = (int*)  alloc((size_t)N * 4);
    float* dinv  = (float*)alloc((size_t)N * 4);
    int*   offs  = (int*)  alloc((size_t)(N + 1) * 4);
    int*   cur   = (int*)  alloc((size_t)N * 4);
    u64*   lb    = (u64*)  alloc((size_t)64 * 8);
    unsigned short* csr  = (unsigned short*)alloc((size_t)E * 2);
    unsigned short* W1f  = (unsigned short*)alloc((size_t)128 * 128 * 2);
    unsigned short* W2f  = (unsigned short*)alloc((size_t)64 * 128 * 2);
    unsigned short* h1   = (unsigned short*)alloc((size_t)N * 128 * 2);
    unsigned short* h2   = (unsigned short*)alloc((size_t)N * 64 * 2);
    float* out = (float*)d_out;

    const int GB = (N + 63) / 64;        // 782
    const int FB = (E + 255) / 256;      // 1954
    const int SB = (N + 1023) / 1024;    // 49
    const int CB = (E / 4 + 255) / 256;  // 489

    init_kernel<<<(N + 255) / 256, 256, 0, stream>>>(W1, W2, W1f, W2f, degi, lb, N);
    count_kernel<<<CB, 256, 0, stream>>>(dst, E, degi);
    scan_lb_kernel<<<SB, 256, 0, stream>>>(degi, N, lb, offs, cur, dinv);
    fillgemm_kernel<<<FB + GB, 256, 0, stream>>>(x, W1f, h1, N, src, dst, E,
                                                 cur, dinv, csr);
    aggmm_kernel<<<(N + 15) / 16, 256, 0, stream>>>(h1, offs, csr, dinv, b1, W2f, h2, N);
    aggout_kernel<<<(N + 3) / 4, 256, 0, stream>>>(h2, offs, csr, dinv, b2, out, N);
}

// Round 12
// 177.974 us; speedup vs baseline: 1.1232x; 1.0957x over previous
//
#include <hip/hip_runtime.h>
#include <hip/hip_bf16.h>
#include <cstddef>

// ---------------------------------------------------------------------------
// 2-layer GCN: h1 = x@W1; hmid = relu(Agg(h1) + b1); h2 = hmid@W2;
// out = Agg(h2) + b2.  Agg = sym-normalized scatter-add with self-loops.
// R8: 6 launches; aggmm 32 lanes/edge x uint2, aggout 16 lanes/edge x uint2
//   = gather-geometry optimum (R6 narrower, R10 wider both lose).
// R11: normalization factoring (dinv folded into producer rows) but 2-byte
//   CSR regressed +4us (sub-dword random scatter/gather).
// R12 (this): keep factoring; CSR back to 4 B int; fill de-atomicized via
//   rank[] captured from count's atomicAdd return (cur[] deleted).
// ---------------------------------------------------------------------------

typedef __attribute__((ext_vector_type(8))) short short8;
typedef __attribute__((ext_vector_type(4))) float f32x4;
typedef unsigned long long u64;

__device__ inline unsigned short f2bf(float f) {
    __hip_bfloat16 b = __float2bfloat16(f);
    return *reinterpret_cast<unsigned short*>(&b);
}
__device__ inline float bf2f_lo(unsigned int u) {
    unsigned int v = u << 16;
    return *reinterpret_cast<float*>(&v);
}
__device__ inline float bf2f_hi(unsigned int u) {
    unsigned int v = u & 0xffff0000u;
    return *reinterpret_cast<float*>(&v);
}
__device__ inline u64 ld_acq64(u64* p) {
    return __hip_atomic_load(p, __ATOMIC_ACQUIRE, __HIP_MEMORY_SCOPE_AGENT);
}
__device__ inline void st_rel64(u64* p, u64 v) {
    __hip_atomic_store(p, v, __ATOMIC_RELEASE, __HIP_MEMORY_SCOPE_AGENT);
}

// ---------------------------------------------------------------------------
// init: zero deg + lookback state; W1/W2 -> global MFMA-B fragment order.
// ---------------------------------------------------------------------------
__global__ __launch_bounds__(256) void init_kernel(const float* __restrict__ W1,
                                                   const float* __restrict__ W2,
                                                   unsigned short* __restrict__ W1f,
                                                   unsigned short* __restrict__ W2f,
                                                   int* __restrict__ deg,
                                                   u64* __restrict__ lb, int N) {
    int idx = blockIdx.x * 256 + threadIdx.x;
    if (idx < N) deg[idx] = 0;
    if (idx < 64) lb[idx] = 0;
    if (idx < 3072) {
        const float* W;
        unsigned short* Wf;
        int n, oct, Nc;
        if (idx < 2048) { W = W1; Wf = W1f; Nc = 128; n = idx >> 4; oct = idx & 15; }
        else { W = W2; Wf = W2f; Nc = 64; int i2 = idx - 2048; n = i2 >> 4; oct = i2 & 15; }
        int k0 = oct * 8;
        int ks = k0 >> 5, quad = (k0 >> 3) & 3, ntg = n >> 4;
        short8 v;
        #pragma unroll
        for (int j = 0; j < 8; j++) v[j] = (short)f2bf(W[(k0 + j) * Nc + n]);
        int off = (((ntg * 4 + ks) * 64) + (n & 15) + 16 * quad) * 8;
        *(short8*)(Wf + off) = v;
    }
}

// count: 4 edges/thread via int4 load; captures within-dst rank from the
// atomicAdd return so fill needs no atomics.
__global__ __launch_bounds__(256) void count_kernel(const int* __restrict__ dst, int E,
                                                    int* __restrict__ deg,
                                                    unsigned short* __restrict__ rank) {
    int i = (blockIdx.x * blockDim.x + threadIdx.x) * 4;
    if (i + 3 < E) {
        int4 d = *(const int4*)(dst + i);
        unsigned short r0 = (unsigned short)atomicAdd(&deg[d.x], 1);
        unsigned short r1 = (unsigned short)atomicAdd(&deg[d.y], 1);
        unsigned short r2 = (unsigned short)atomicAdd(&deg[d.z], 1);
        unsigned short r3 = (unsigned short)atomicAdd(&deg[d.w], 1);
        *(ushort4*)(rank + i) = make_ushort4(r0, r1, r2, r3);
    } else {
        for (; i < E; i++) rank[i] = (unsigned short)atomicAdd(&deg[dst[i]], 1);
    }
}

// ---------------------------------------------------------------------------
// scan_lb: one-pass exclusive scan of deg via decoupled lookback (49 peer
// blocks, co-resident). Writes offs, dinv.
// ---------------------------------------------------------------------------
__global__ __launch_bounds__(256) void scan_lb_kernel(const int* __restrict__ deg, int N,
                                                      u64* __restrict__ lb,
                                                      int* __restrict__ offs,
                                                      float* __restrict__ dinv) {
    __shared__ int ws[4];
    __shared__ int s_prefix;
    int tid = threadIdx.x;
    int sb = blockIdx.x;
    int SB = gridDim.x;
    int lane = tid & 63;
    int wv = tid >> 6;

    int i = sb * 1024 + tid * 4;
    int v0 = (i + 0 < N) ? deg[i + 0] : 0;
    int v1 = (i + 1 < N) ? deg[i + 1] : 0;
    int v2 = (i + 2 < N) ? deg[i + 2] : 0;
    int v3 = (i + 3 < N) ? deg[i + 3] : 0;
    int tsum = v0 + v1 + v2 + v3;
    int xs = tsum;
    #pragma unroll
    for (int off = 1; off < 64; off <<= 1) {
        int y = __shfl_up(xs, off, 64);
        if (lane >= off) xs += y;
    }
    if (lane == 63) ws[wv] = xs;
    __syncthreads();
    int wprefix = 0;
    #pragma unroll
    for (int w2 = 0; w2 < 4; w2++) wprefix += (w2 < wv) ? ws[w2] : 0;
    int chunk_total = ws[0] + ws[1] + ws[2] + ws[3];

    if (tid == 0) {
        st_rel64(&lb[sb], ((u64)(unsigned)chunk_total << 2) | 1ull);
        int prefix = 0;
        for (int pred = sb - 1; pred >= 0; --pred) {
            u64 v;
            do {
                v = ld_acq64(&lb[pred]);
                if ((v & 3) == 0) __builtin_amdgcn_s_sleep(1);
            } while ((v & 3) == 0);
            prefix += (int)(unsigned)(v >> 2);
            if ((v & 3) == 2) break;
        }
        st_rel64(&lb[sb], ((u64)(unsigned)(prefix + chunk_total) << 2) | 2ull);
        s_prefix = prefix;
    }
    __syncthreads();

    int carry = s_prefix;
    int e0 = carry + wprefix + xs - tsum;
    int e1 = e0 + v0, e2 = e1 + v1, e3 = e2 + v2;
    if (i + 0 < N) { offs[i + 0] = e0; dinv[i + 0] = rsqrtf((float)(v0 + 1)); }
    if (i + 1 < N) { offs[i + 1] = e1; dinv[i + 1] = rsqrtf((float)(v1 + 1)); }
    if (i + 2 < N) { offs[i + 2] = e2; dinv[i + 2] = rsqrtf((float)(v2 + 1)); }
    if (i + 3 < N) { offs[i + 3] = e3; dinv[i + 3] = rsqrtf((float)(v3 + 1)); }
    if (sb == SB - 1 && tid == 0) offs[N] = carry + chunk_total;
}

// ---------------------------------------------------------------------------
// fillgemm: blocks [0, FB) = CSR fill (no atomics: pos = offs[d] + rank[e]);
//           blocks [FB, FB+GB) = gemm1 with dinv-scaled epilogue.
// Independent -> no handshake.
// ---------------------------------------------------------------------------
__global__ __launch_bounds__(256) void fillgemm_kernel(
    const float* __restrict__ x, const unsigned short* __restrict__ W1f,
    unsigned short* __restrict__ h1, int N,
    const int* __restrict__ src, const int* __restrict__ dst, int E,
    const int* __restrict__ offs, const unsigned short* __restrict__ rank,
    const float* __restrict__ dinv, int* __restrict__ csr) {

    const int FB = (E + 255) / 256;
    int b = blockIdx.x;
    int tid = threadIdx.x;

    __shared__ unsigned short As[64 * 128];  // 16 KB (gemm blocks only)
    __shared__ float sdinv[64];

    if (b < FB) {
        // ---------------- fill ----------------
        int i = b * 256 + tid;
        if (i < E) {
            int s = src[i];
            int d = dst[i];
            int pos = offs[d] + (int)rank[i];
            csr[pos] = s;
        }
        return;
    }

    // ---------------- gemm1: h1 = dinv . (x @ W1) ----------------
    constexpr int K = 128, BN = 128;
    int lane = tid & 63;
    int w = tid >> 6;
    int row0 = (b - FB) * 64;

    if (tid < 64) {
        int gr = row0 + tid;
        sdinv[tid] = (gr < N) ? dinv[gr] : 0.f;
    }

    short8 bfr[2][4];
    #pragma unroll
    for (int nl = 0; nl < 2; nl++)
        #pragma unroll
        for (int ks = 0; ks < 4; ks++)
            bfr[nl][ks] = *(const short8*)(W1f + ((((w * 2 + nl) * 4 + ks) * 64) + lane) * 8);

    #pragma unroll
    for (int it = 0; it < 8; it++) {
        int idx = it * 256 + tid;
        int row = idx >> 5, kq = idx & 31;
        int k0 = kq * 4;
        int ks = k0 >> 5, quad = (k0 >> 3) & 3, j0 = k0 & 7, mt = row >> 4;
        ushort4 o = make_ushort4(0, 0, 0, 0);
        int gr = row0 + row;
        if (gr < N) {
            float4 a = *(const float4*)(x + (size_t)gr * K + k0);
            o.x = f2bf(a.x); o.y = f2bf(a.y); o.z = f2bf(a.z); o.w = f2bf(a.w);
        }
        int off = (((mt * 4 + ks) * 64) + (row & 15) + 16 * quad) * 8 + j0;
        *(ushort4*)(As + off) = o;
    }
    __syncthreads();

    f32x4 acc[4][2];
    #pragma unroll
    for (int mt = 0; mt < 4; mt++)
        #pragma unroll
        for (int nl = 0; nl < 2; nl++) acc[mt][nl] = (f32x4){0.f, 0.f, 0.f, 0.f};

    #pragma unroll
    for (int ks = 0; ks < 4; ks++) {
        short8 af[4];
        #pragma unroll
        for (int mt = 0; mt < 4; mt++)
            af[mt] = *(const short8*)(As + (((mt * 4 + ks) * 64) + lane) * 8);
        #pragma unroll
        for (int mt = 0; mt < 4; mt++)
            #pragma unroll
            for (int nl = 0; nl < 2; nl++)
                acc[mt][nl] = __builtin_amdgcn_mfma_f32_16x16x32_bf16(
                    af[mt], bfr[nl][ks], acc[mt][nl], 0, 0, 0);
    }

    int col16 = lane & 15;
    int rowq = lane >> 4;
    #pragma unroll
    for (int mt = 0; mt < 4; mt++) {
        #pragma unroll
        for (int nl = 0; nl < 2; nl++) {
            int gc = (w * 2 + nl) * 16 + col16;
            #pragma unroll
            for (int r = 0; r < 4; r++) {
                int lr = mt * 16 + rowq * 4 + r;
                int gr = row0 + lr;
                if (gr < N) h1[(size_t)gr * BN + gc] = f2bf(acc[mt][nl][r] * sdinv[lr]);
            }
        }
    }
}

// ---------------------------------------------------------------------------
// aggmm: fused Agg(layer1) + bias + ReLU + GEMM2, epilogue-scaled by dinv.
// hmid[d] = relu(dinv[d]*(h1'[d] + sum_e h1'[src]) + b1); h2' = dinv.(hmid@W2)
// Block = 4 waves = 16 nodes (4/wave sequential). 32 lanes/edge (uint2 =
// 4 bf16), 2 edge slots x unroll 4 (8 edges/iter); reduce shfl_xor(32).
// ---------------------------------------------------------------------------
__global__ __launch_bounds__(256) void aggmm_kernel(const unsigned short* __restrict__ h1,
                                                    const int* __restrict__ offs,
                                                    const int* __restrict__ csr,
                                                    const float* __restrict__ dinv,
                                                    const float* __restrict__ b1,
                                                    const unsigned short* __restrict__ W2f,
                                                    unsigned short* __restrict__ h2,
                                                    int n) {
    __shared__ unsigned short As[4 * 64 * 8];  // 4 KB, one 16x128 A-tile

    int tid = threadIdx.x;
    int t = tid & 63;
    int w = tid >> 6;
    int p = t >> 5;      // edge slot (0/1)
    int t5 = t & 31;     // feature quad index (4 bf16)
    int nodebase = blockIdx.x * 16;

    short8 bw[4];
    #pragma unroll
    for (int ks = 0; ks < 4; ks++)
        bw[ks] = *(const short8*)(W2f + (((w * 4 + ks) * 64) + t) * 8);

    float4 bias = *(const float4*)(b1 + t5 * 4);

    #pragma unroll
    for (int i = 0; i < 4; i++) {
        int row16 = w * 4 + i;
        int node = nodebase + row16;
        float a0 = 0.f, a1 = 0.f, a2 = 0.f, a3 = 0.f;
        float di = 0.f;
        if (node < n) {
            di = dinv[node];
            if (p == 0) {
                uint2 su = *(const uint2*)(h1 + (size_t)node * 128 + t5 * 4);
                a0 = bf2f_lo(su.x); a1 = bf2f_hi(su.x);
                a2 = bf2f_lo(su.y); a3 = bf2f_hi(su.y);
            }
            int e0 = offs[node];
            int e1 = offs[node + 1];
            int iters = (e1 - e0 + 7) >> 3;
            for (int it = 0; it < iters; it++) {
                int eb = e0 + it * 8;
                #pragma unroll
                for (int j = 0; j < 4; j++) {
                    int ee = eb + j * 2 + p;
                    int ec = min(ee, e1 - 1);
                    int s = csr[ec];
                    float wgt = (ee < e1) ? 1.f : 0.f;
                    uint2 hu = *(const uint2*)(h1 + (size_t)s * 128 + t5 * 4);
                    a0 += bf2f_lo(hu.x) * wgt; a1 += bf2f_hi(hu.x) * wgt;
                    a2 += bf2f_lo(hu.y) * wgt; a3 += bf2f_hi(hu.y) * wgt;
                }
            }
        }
        a0 += __shfl_xor(a0, 32, 64);
        a1 += __shfl_xor(a1, 32, 64);
        a2 += __shfl_xor(a2, 32, 64);
        a3 += __shfl_xor(a3, 32, 64);
        if (p == 0) {
            if (node < n) {
                a0 = fmaxf(a0 * di + bias.x, 0.f);
                a1 = fmaxf(a1 * di + bias.y, 0.f);
                a2 = fmaxf(a2 * di + bias.z, 0.f);
                a3 = fmaxf(a3 * di + bias.w, 0.f);
            }
            int k0 = t5 * 4;
            int ks = k0 >> 5, quad = (k0 >> 3) & 3, j0 = k0 & 7;
            ushort4 pk4 = make_ushort4(f2bf(a0), f2bf(a1), f2bf(a2), f2bf(a3));
            *(ushort4*)(As + ((ks * 64) + row16 + 16 * quad) * 8 + j0) = pk4;
        }
    }
    __syncthreads();

    f32x4 acc = (f32x4){0.f, 0.f, 0.f, 0.f};
    #pragma unroll
    for (int ks = 0; ks < 4; ks++) {
        short8 af = *(const short8*)(As + ((ks * 64) + t) * 8);
        acc = __builtin_amdgcn_mfma_f32_16x16x32_bf16(af, bw[ks], acc, 0, 0, 0);
    }

    int col = w * 16 + (t & 15);
    int rowq = t >> 4;
    #pragma unroll
    for (int r = 0; r < 4; r++) {
        int gr = nodebase + rowq * 4 + r;
        if (gr < n) h2[(size_t)gr * 64 + col] = f2bf(acc[r] * dinv[gr]);
    }
}

// ---------------------------------------------------------------------------
// aggout: out[d] = dinv[d]*(h2'[d] + sum_e h2'[src]) + b2, fp32 out.
// One node/wave; 16 lanes/edge (uint2 = 4 bf16), 4 edge slots x unroll 2
// (8 edges/iter); reduce shfl_xor(16,32); float4 epilogue.
// ---------------------------------------------------------------------------
__global__ __launch_bounds__(256) void aggout_kernel(const unsigned short* __restrict__ h2,
                                                     const int* __restrict__ offs,
                                                     const int* __restrict__ csr,
                                                     const float* __restrict__ dinv,
                                                     const float* __restrict__ b2,
                                                     float* __restrict__ out, int n) {
    int tid = threadIdx.x;
    int t = tid & 63;
    int w = tid >> 6;
    int node = blockIdx.x * 4 + w;
    if (node >= n) return;
    int p = t >> 4;      // edge slot (0..3)
    int t4 = t & 15;     // feature quad index

    float a0 = 0.f, a1 = 0.f, a2 = 0.f, a3 = 0.f;
    float di = dinv[node];
    if (p == 0) {
        uint2 su = *(const uint2*)(h2 + (size_t)node * 64 + t4 * 4);
        a0 = bf2f_lo(su.x); a1 = bf2f_hi(su.x);
        a2 = bf2f_lo(su.y); a3 = bf2f_hi(su.y);
    }

    int e0 = offs[node];
    int e1 = offs[node + 1];
    int iters = (e1 - e0 + 7) >> 3;
    for (int it = 0; it < iters; it++) {
        int eb = e0 + it * 8;
        #pragma unroll
        for (int j = 0; j < 2; j++) {
            int ee = eb + j * 4 + p;
            int ec = min(ee, e1 - 1);
            int s = csr[ec];
            float wgt = (ee < e1) ? 1.f : 0.f;
            uint2 hu = *(const uint2*)(h2 + (size_t)s * 64 + t4 * 4);
            a0 += bf2f_lo(hu.x) * wgt; a1 += bf2f_hi(hu.x) * wgt;
            a2 += bf2f_lo(hu.y) * wgt; a3 += bf2f_hi(hu.y) * wgt;
        }
    }
    a0 += __shfl_xor(a0, 16, 64); a1 += __shfl_xor(a1, 16, 64);
    a2 += __shfl_xor(a2, 16, 64); a3 += __shfl_xor(a3, 16, 64);
    a0 += __shfl_xor(a0, 32, 64); a1 += __shfl_xor(a1, 32, 64);
    a2 += __shfl_xor(a2, 32, 64); a3 += __shfl_xor(a3, 32, 64);
    if (p == 0) {
        float4 bb = *(const float4*)(b2 + t4 * 4);
        *(float4*)(out + (size_t)node * 64 + t4 * 4) =
            make_float4(a0 * di + bb.x, a1 * di + bb.y, a2 * di + bb.z, a3 * di + bb.w);
    }
}

extern "C" void kernel_launch(void* const* d_in, const int* in_sizes, int n_in,
                              void* d_out, int out_size, void* d_ws, size_t ws_size,
                              hipStream_t stream) {
    const float* x  = (const float*)d_in[0];
    const int*   ei = (const int*)d_in[1];
    const float* W1 = (const float*)d_in[2];
    const float* b1 = (const float*)d_in[3];
    const float* W2 = (const float*)d_in[4];
    const float* b2 = (const float*)d_in[5];

    const int N = in_sizes[0] / 128;   // 50000
    const int E = in_sizes[1] / 2;     // 500000
    const int* src = ei;
    const int* dst = ei + E;

    char* p = (char*)d_ws;
    auto alloc = [&](size_t bytes) {
        char* r = p;
        p += (bytes + 255) & ~(size_t)255;
        return r;
    };
    int*   degi  = (int*)  alloc((size_t)N * 4);
    float* dinv  = (float*)alloc((size_t)N * 4);
    int*   offs  = (int*)  alloc((size_t)(N + 1) * 4);
    u64*   lb    = (u64*)  alloc((size_t)64 * 8);
    unsigned short* rank = (unsigned short*)alloc((size_t)E * 2);
    int*            csr  = (int*)alloc((size_t)E * 4);
    unsigned short* W1f  = (unsigned short*)alloc((size_t)128 * 128 * 2);
    unsigned short* W2f  = (unsigned short*)alloc((size_t)64 * 128 * 2);
    unsigned short* h1   = (unsigned short*)alloc((size_t)N * 128 * 2);
    unsigned short* h2   = (unsigned short*)alloc((size_t)N * 64 * 2);
    float* out = (float*)d_out;

    const int GB = (N + 63) / 64;        // 782
    const int FB = (E + 255) / 256;      // 1954
    const int SB = (N + 1023) / 1024;    // 49
    const int CB = (E / 4 + 255) / 256;  // 489

    init_kernel<<<(N + 255) / 256, 256, 0, stream>>>(W1, W2, W1f, W2f, degi, lb, N);
    count_kernel<<<CB, 256, 0, stream>>>(dst, E, degi, rank);
    scan_lb_kernel<<<SB, 256, 0, stream>>>(degi, N, lb, offs, dinv);
    fillgemm_kernel<<<FB + GB, 256, 0, stream>>>(x, W1f, h1, N, src, dst, E,
                                                 offs, rank, dinv, csr);
    aggmm_kernel<<<(N + 15) / 16, 256, 0, stream>>>(h1, offs, csr, dinv, b1, W2f, h2, N);
    aggout_kernel<<<(N + 3) / 4, 256, 0, stream>>>(h2, offs, csr, dinv, b2, out, N);
}

// Round 13
// 177.478 us; speedup vs baseline: 1.1264x; 1.0028x over previous
//
#include <hip/hip_runtime.h>
#include <hip/hip_bf16.h>
#include <cstddef>

// ---------------------------------------------------------------------------
// 2-layer GCN: h1 = x@W1; hmid = relu(Agg(h1) + b1); h2 = hmid@W2;
// out = Agg(h2) + b2.  Agg = sym-normalized scatter-add with self-loops.
// R8: aggmm 32 lanes/edge x uint2, aggout 16 lanes/edge x uint2 = gather
//   optimum (R6 narrower, R10 wider both lose). R7: no intra-kernel spin sync.
// R11/R12: normalization factoring (dinv folded into producer rows), 4 B CSR,
//   fill de-atomicized via rank[] from count's atomicAdd return. 178 us.
// R13 (this): init_kernel deleted -- deg zero via hipMemsetAsync, lb zero +
//   wt_frag folded into count_kernel's extra blocks (independent work in the
//   atomic-latency shadow). 6 kernels -> 5 + memset.
// ---------------------------------------------------------------------------

typedef __attribute__((ext_vector_type(8))) short short8;
typedef __attribute__((ext_vector_type(4))) float f32x4;
typedef unsigned long long u64;

__device__ inline unsigned short f2bf(float f) {
    __hip_bfloat16 b = __float2bfloat16(f);
    return *reinterpret_cast<unsigned short*>(&b);
}
__device__ inline float bf2f_lo(unsigned int u) {
    unsigned int v = u << 16;
    return *reinterpret_cast<float*>(&v);
}
__device__ inline float bf2f_hi(unsigned int u) {
    unsigned int v = u & 0xffff0000u;
    return *reinterpret_cast<float*>(&v);
}
__device__ inline u64 ld_acq64(u64* p) {
    return __hip_atomic_load(p, __ATOMIC_ACQUIRE, __HIP_MEMORY_SCOPE_AGENT);
}
__device__ inline void st_rel64(u64* p, u64 v) {
    __hip_atomic_store(p, v, __ATOMIC_RELEASE, __HIP_MEMORY_SCOPE_AGENT);
}

// ---------------------------------------------------------------------------
// count: blocks [0, CB) count 4 edges/thread (int4 load), capturing
// within-dst rank from atomicAdd return (fill needs no atomics).
// Blocks [CB, CB+12): W1/W2 -> global MFMA-B fragment order + lb zeroing
// (lb is read only by scan, after this kernel's boundary).
// ---------------------------------------------------------------------------
__global__ __launch_bounds__(256) void count_kernel(const int* __restrict__ dst, int E,
                                                    int* __restrict__ deg,
                                                    unsigned short* __restrict__ rank,
                                                    const float* __restrict__ W1,
                                                    const float* __restrict__ W2,
                                                    unsigned short* __restrict__ W1f,
                                                    unsigned short* __restrict__ W2f,
                                                    u64* __restrict__ lb, int CB) {
    int b = blockIdx.x;
    int tid = threadIdx.x;
    if (b >= CB) {
        int idx = (b - CB) * 256 + tid;
        if (idx < 64) lb[idx] = 0;
        if (idx < 3072) {
            const float* W;
            unsigned short* Wf;
            int n, oct, Nc;
            if (idx < 2048) { W = W1; Wf = W1f; Nc = 128; n = idx >> 4; oct = idx & 15; }
            else { W = W2; Wf = W2f; Nc = 64; int i2 = idx - 2048; n = i2 >> 4; oct = i2 & 15; }
            int k0 = oct * 8;
            int ks = k0 >> 5, quad = (k0 >> 3) & 3, ntg = n >> 4;
            short8 v;
            #pragma unroll
            for (int j = 0; j < 8; j++) v[j] = (short)f2bf(W[(k0 + j) * Nc + n]);
            int off = (((ntg * 4 + ks) * 64) + (n & 15) + 16 * quad) * 8;
            *(short8*)(Wf + off) = v;
        }
        return;
    }
    int i = (b * 256 + tid) * 4;
    if (i + 3 < E) {
        int4 d = *(const int4*)(dst + i);
        unsigned short r0 = (unsigned short)atomicAdd(&deg[d.x], 1);
        unsigned short r1 = (unsigned short)atomicAdd(&deg[d.y], 1);
        unsigned short r2 = (unsigned short)atomicAdd(&deg[d.z], 1);
        unsigned short r3 = (unsigned short)atomicAdd(&deg[d.w], 1);
        *(ushort4*)(rank + i) = make_ushort4(r0, r1, r2, r3);
    } else {
        for (; i < E; i++) rank[i] = (unsigned short)atomicAdd(&deg[dst[i]], 1);
    }
}

// ---------------------------------------------------------------------------
// scan_lb: one-pass exclusive scan of deg via decoupled lookback (49 peer
// blocks, co-resident). Writes offs, dinv.
// ---------------------------------------------------------------------------
__global__ __launch_bounds__(256) void scan_lb_kernel(const int* __restrict__ deg, int N,
                                                      u64* __restrict__ lb,
                                                      int* __restrict__ offs,
                                                      float* __restrict__ dinv) {
    __shared__ int ws[4];
    __shared__ int s_prefix;
    int tid = threadIdx.x;
    int sb = blockIdx.x;
    int SB = gridDim.x;
    int lane = tid & 63;
    int wv = tid >> 6;

    int i = sb * 1024 + tid * 4;
    int v0 = (i + 0 < N) ? deg[i + 0] : 0;
    int v1 = (i + 1 < N) ? deg[i + 1] : 0;
    int v2 = (i + 2 < N) ? deg[i + 2] : 0;
    int v3 = (i + 3 < N) ? deg[i + 3] : 0;
    int tsum = v0 + v1 + v2 + v3;
    int xs = tsum;
    #pragma unroll
    for (int off = 1; off < 64; off <<= 1) {
        int y = __shfl_up(xs, off, 64);
        if (lane >= off) xs += y;
    }
    if (lane == 63) ws[wv] = xs;
    __syncthreads();
    int wprefix = 0;
    #pragma unroll
    for (int w2 = 0; w2 < 4; w2++) wprefix += (w2 < wv) ? ws[w2] : 0;
    int chunk_total = ws[0] + ws[1] + ws[2] + ws[3];

    if (tid == 0) {
        st_rel64(&lb[sb], ((u64)(unsigned)chunk_total << 2) | 1ull);
        int prefix = 0;
        for (int pred = sb - 1; pred >= 0; --pred) {
            u64 v;
            do {
                v = ld_acq64(&lb[pred]);
                if ((v & 3) == 0) __builtin_amdgcn_s_sleep(1);
            } while ((v & 3) == 0);
            prefix += (int)(unsigned)(v >> 2);
            if ((v & 3) == 2) break;
        }
        st_rel64(&lb[sb], ((u64)(unsigned)(prefix + chunk_total) << 2) | 2ull);
        s_prefix = prefix;
    }
    __syncthreads();

    int carry = s_prefix;
    int e0 = carry + wprefix + xs - tsum;
    int e1 = e0 + v0, e2 = e1 + v1, e3 = e2 + v2;
    if (i + 0 < N) { offs[i + 0] = e0; dinv[i + 0] = rsqrtf((float)(v0 + 1)); }
    if (i + 1 < N) { offs[i + 1] = e1; dinv[i + 1] = rsqrtf((float)(v1 + 1)); }
    if (i + 2 < N) { offs[i + 2] = e2; dinv[i + 2] = rsqrtf((float)(v2 + 1)); }
    if (i + 3 < N) { offs[i + 3] = e3; dinv[i + 3] = rsqrtf((float)(v3 + 1)); }
    if (sb == SB - 1 && tid == 0) offs[N] = carry + chunk_total;
}

// ---------------------------------------------------------------------------
// fillgemm: blocks [0, FB) = CSR fill (no atomics: pos = offs[d] + rank[e]);
//           blocks [FB, FB+GB) = gemm1 with dinv-scaled epilogue.
// Independent -> no handshake.
// ---------------------------------------------------------------------------
__global__ __launch_bounds__(256) void fillgemm_kernel(
    const float* __restrict__ x, const unsigned short* __restrict__ W1f,
    unsigned short* __restrict__ h1, int N,
    const int* __restrict__ src, const int* __restrict__ dst, int E,
    const int* __restrict__ offs, const unsigned short* __restrict__ rank,
    const float* __restrict__ dinv, int* __restrict__ csr) {

    const int FB = (E + 255) / 256;
    int b = blockIdx.x;
    int tid = threadIdx.x;

    __shared__ unsigned short As[64 * 128];  // 16 KB (gemm blocks only)
    __shared__ float sdinv[64];

    if (b < FB) {
        // ---------------- fill ----------------
        int i = b * 256 + tid;
        if (i < E) {
            int s = src[i];
            int d = dst[i];
            int pos = offs[d] + (int)rank[i];
            csr[pos] = s;
        }
        return;
    }

    // ---------------- gemm1: h1 = dinv . (x @ W1) ----------------
    constexpr int K = 128, BN = 128;
    int lane = tid & 63;
    int w = tid >> 6;
    int row0 = (b - FB) * 64;

    if (tid < 64) {
        int gr = row0 + tid;
        sdinv[tid] = (gr < N) ? dinv[gr] : 0.f;
    }

    short8 bfr[2][4];
    #pragma unroll
    for (int nl = 0; nl < 2; nl++)
        #pragma unroll
        for (int ks = 0; ks < 4; ks++)
            bfr[nl][ks] = *(const short8*)(W1f + ((((w * 2 + nl) * 4 + ks) * 64) + lane) * 8);

    #pragma unroll
    for (int it = 0; it < 8; it++) {
        int idx = it * 256 + tid;
        int row = idx >> 5, kq = idx & 31;
        int k0 = kq * 4;
        int ks = k0 >> 5, quad = (k0 >> 3) & 3, j0 = k0 & 7, mt = row >> 4;
        ushort4 o = make_ushort4(0, 0, 0, 0);
        int gr = row0 + row;
        if (gr < N) {
            float4 a = *(const float4*)(x + (size_t)gr * K + k0);
            o.x = f2bf(a.x); o.y = f2bf(a.y); o.z = f2bf(a.z); o.w = f2bf(a.w);
        }
        int off = (((mt * 4 + ks) * 64) + (row & 15) + 16 * quad) * 8 + j0;
        *(ushort4*)(As + off) = o;
    }
    __syncthreads();

    f32x4 acc[4][2];
    #pragma unroll
    for (int mt = 0; mt < 4; mt++)
        #pragma unroll
        for (int nl = 0; nl < 2; nl++) acc[mt][nl] = (f32x4){0.f, 0.f, 0.f, 0.f};

    #pragma unroll
    for (int ks = 0; ks < 4; ks++) {
        short8 af[4];
        #pragma unroll
        for (int mt = 0; mt < 4; mt++)
            af[mt] = *(const short8*)(As + (((mt * 4 + ks) * 64) + lane) * 8);
        #pragma unroll
        for (int mt = 0; mt < 4; mt++)
            #pragma unroll
            for (int nl = 0; nl < 2; nl++)
                acc[mt][nl] = __builtin_amdgcn_mfma_f32_16x16x32_bf16(
                    af[mt], bfr[nl][ks], acc[mt][nl], 0, 0, 0);
    }

    int col16 = lane & 15;
    int rowq = lane >> 4;
    #pragma unroll
    for (int mt = 0; mt < 4; mt++) {
        #pragma unroll
        for (int nl = 0; nl < 2; nl++) {
            int gc = (w * 2 + nl) * 16 + col16;
            #pragma unroll
            for (int r = 0; r < 4; r++) {
                int lr = mt * 16 + rowq * 4 + r;
                int gr = row0 + lr;
                if (gr < N) h1[(size_t)gr * BN + gc] = f2bf(acc[mt][nl][r] * sdinv[lr]);
            }
        }
    }
}

// ---------------------------------------------------------------------------
// aggmm: fused Agg(layer1) + bias + ReLU + GEMM2, epilogue-scaled by dinv.
// hmid[d] = relu(dinv[d]*(h1'[d] + sum_e h1'[src]) + b1); h2' = dinv.(hmid@W2)
// Block = 4 waves = 16 nodes (4/wave sequential). 32 lanes/edge (uint2 =
// 4 bf16), 2 edge slots x unroll 4 (8 edges/iter); reduce shfl_xor(32).
// ---------------------------------------------------------------------------
__global__ __launch_bounds__(256) void aggmm_kernel(const unsigned short* __restrict__ h1,
                                                    const int* __restrict__ offs,
                                                    const int* __restrict__ csr,
                                                    const float* __restrict__ dinv,
                                                    const float* __restrict__ b1,
                                                    const unsigned short* __restrict__ W2f,
                                                    unsigned short* __restrict__ h2,
                                                    int n) {
    __shared__ unsigned short As[4 * 64 * 8];  // 4 KB, one 16x128 A-tile

    int tid = threadIdx.x;
    int t = tid & 63;
    int w = tid >> 6;
    int p = t >> 5;      // edge slot (0/1)
    int t5 = t & 31;     // feature quad index (4 bf16)
    int nodebase = blockIdx.x * 16;

    short8 bw[4];
    #pragma unroll
    for (int ks = 0; ks < 4; ks++)
        bw[ks] = *(const short8*)(W2f + (((w * 4 + ks) * 64) + t) * 8);

    float4 bias = *(const float4*)(b1 + t5 * 4);

    #pragma unroll
    for (int i = 0; i < 4; i++) {
        int row16 = w * 4 + i;
        int node = nodebase + row16;
        float a0 = 0.f, a1 = 0.f, a2 = 0.f, a3 = 0.f;
        float di = 0.f;
        if (node < n) {
            di = dinv[node];
            if (p == 0) {
                uint2 su = *(const uint2*)(h1 + (size_t)node * 128 + t5 * 4);
                a0 = bf2f_lo(su.x); a1 = bf2f_hi(su.x);
                a2 = bf2f_lo(su.y); a3 = bf2f_hi(su.y);
            }
            int e0 = offs[node];
            int e1 = offs[node + 1];
            int iters = (e1 - e0 + 7) >> 3;
            for (int it = 0; it < iters; it++) {
                int eb = e0 + it * 8;
                #pragma unroll
                for (int j = 0; j < 4; j++) {
                    int ee = eb + j * 2 + p;
                    int ec = min(ee, e1 - 1);
                    int s = csr[ec];
                    float wgt = (ee < e1) ? 1.f : 0.f;
                    uint2 hu = *(const uint2*)(h1 + (size_t)s * 128 + t5 * 4);
                    a0 += bf2f_lo(hu.x) * wgt; a1 += bf2f_hi(hu.x) * wgt;
                    a2 += bf2f_lo(hu.y) * wgt; a3 += bf2f_hi(hu.y) * wgt;
                }
            }
        }
        a0 += __shfl_xor(a0, 32, 64);
        a1 += __shfl_xor(a1, 32, 64);
        a2 += __shfl_xor(a2, 32, 64);
        a3 += __shfl_xor(a3, 32, 64);
        if (p == 0) {
            if (node < n) {
                a0 = fmaxf(a0 * di + bias.x, 0.f);
                a1 = fmaxf(a1 * di + bias.y, 0.f);
                a2 = fmaxf(a2 * di + bias.z, 0.f);
                a3 = fmaxf(a3 * di + bias.w, 0.f);
            }
            int k0 = t5 * 4;
            int ks = k0 >> 5, quad = (k0 >> 3) & 3, j0 = k0 & 7;
            ushort4 pk4 = make_ushort4(f2bf(a0), f2bf(a1), f2bf(a2), f2bf(a3));
            *(ushort4*)(As + ((ks * 64) + row16 + 16 * quad) * 8 + j0) = pk4;
        }
    }
    __syncthreads();

    f32x4 acc = (f32x4){0.f, 0.f, 0.f, 0.f};
    #pragma unroll
    for (int ks = 0; ks < 4; ks++) {
        short8 af = *(const short8*)(As + ((ks * 64) + t) * 8);
        acc = __builtin_amdgcn_mfma_f32_16x16x32_bf16(af, bw[ks], acc, 0, 0, 0);
    }

    int col = w * 16 + (t & 15);
    int rowq = t >> 4;
    #pragma unroll
    for (int r = 0; r < 4; r++) {
        int gr = nodebase + rowq * 4 + r;
        if (gr < n) h2[(size_t)gr * 64 + col] = f2bf(acc[r] * dinv[gr]);
    }
}

// ---------------------------------------------------------------------------
// aggout: out[d] = dinv[d]*(h2'[d] + sum_e h2'[src]) + b2, fp32 out.
// One node/wave; 16 lanes/edge (uint2 = 4 bf16), 4 edge slots x unroll 2
// (8 edges/iter); reduce shfl_xor(16,32); float4 epilogue.
// ---------------------------------------------------------------------------
__global__ __launch_bounds__(256) void aggout_kernel(const unsigned short* __restrict__ h2,
                                                     const int* __restrict__ offs,
                                                     const int* __restrict__ csr,
                                                     const float* __restrict__ dinv,
                                                     const float* __restrict__ b2,
                                                     float* __restrict__ out, int n) {
    int tid = threadIdx.x;
    int t = tid & 63;
    int w = tid >> 6;
    int node = blockIdx.x * 4 + w;
    if (node >= n) return;
    int p = t >> 4;      // edge slot (0..3)
    int t4 = t & 15;     // feature quad index

    float a0 = 0.f, a1 = 0.f, a2 = 0.f, a3 = 0.f;
    float di = dinv[node];
    if (p == 0) {
        uint2 su = *(const uint2*)(h2 + (size_t)node * 64 + t4 * 4);
        a0 = bf2f_lo(su.x); a1 = bf2f_hi(su.x);
        a2 = bf2f_lo(su.y); a3 = bf2f_hi(su.y);
    }

    int e0 = offs[node];
    int e1 = offs[node + 1];
    int iters = (e1 - e0 + 7) >> 3;
    for (int it = 0; it < iters; it++) {
        int eb = e0 + it * 8;
        #pragma unroll
        for (int j = 0; j < 2; j++) {
            int ee = eb + j * 4 + p;
            int ec = min(ee, e1 - 1);
            int s = csr[ec];
            float wgt = (ee < e1) ? 1.f : 0.f;
            uint2 hu = *(const uint2*)(h2 + (size_t)s * 64 + t4 * 4);
            a0 += bf2f_lo(hu.x) * wgt; a1 += bf2f_hi(hu.x) * wgt;
            a2 += bf2f_lo(hu.y) * wgt; a3 += bf2f_hi(hu.y) * wgt;
        }
    }
    a0 += __shfl_xor(a0, 16, 64); a1 += __shfl_xor(a1, 16, 64);
    a2 += __shfl_xor(a2, 16, 64); a3 += __shfl_xor(a3, 16, 64);
    a0 += __shfl_xor(a0, 32, 64); a1 += __shfl_xor(a1, 32, 64);
    a2 += __shfl_xor(a2, 32, 64); a3 += __shfl_xor(a3, 32, 64);
    if (p == 0) {
        float4 bb = *(const float4*)(b2 + t4 * 4);
        *(float4*)(out + (size_t)node * 64 + t4 * 4) =
            make_float4(a0 * di + bb.x, a1 * di + bb.y, a2 * di + bb.z, a3 * di + bb.w);
    }
}

extern "C" void kernel_launch(void* const* d_in, const int* in_sizes, int n_in,
                              void* d_out, int out_size, void* d_ws, size_t ws_size,
                              hipStream_t stream) {
    const float* x  = (const float*)d_in[0];
    const int*   ei = (const int*)d_in[1];
    const float* W1 = (const float*)d_in[2];
    const float* b1 = (const float*)d_in[3];
    const float* W2 = (const float*)d_in[4];
    const float* b2 = (const float*)d_in[5];

    const int N = in_sizes[0] / 128;   // 50000
    const int E = in_sizes[1] / 2;     // 500000
    const int* src = ei;
    const int* dst = ei + E;

    char* p = (char*)d_ws;
    auto alloc = [&](size_t bytes) {
        char* r = p;
        p += (bytes + 255) & ~(size_t)255;
        return r;
    };
    int*   degi  = (int*)  alloc((size_t)N * 4);
    float* dinv  = (float*)alloc((size_t)N * 4);
    int*   offs  = (int*)  alloc((size_t)(N + 1) * 4);
    u64*   lb    = (u64*)  alloc((size_t)64 * 8);
    unsigned short* rank = (unsigned short*)alloc((size_t)E * 2);
    int*            csr  = (int*)alloc((size_t)E * 4);
    unsigned short* W1f  = (unsigned short*)alloc((size_t)128 * 128 * 2);
    unsigned short* W2f  = (unsigned short*)alloc((size_t)64 * 128 * 2);
    unsigned short* h1   = (unsigned short*)alloc((size_t)N * 128 * 2);
    unsigned short* h2   = (unsigned short*)alloc((size_t)N * 64 * 2);
    float* out = (float*)d_out;

    const int GB = (N + 63) / 64;        // 782
    const int FB = (E + 255) / 256;      // 1954
    const int SB = (N + 1023) / 1024;    // 49
    const int CB = (E / 4 + 255) / 256;  // 489

    hipMemsetAsync(degi, 0, (size_t)N * 4, stream);
    count_kernel<<<CB + 12, 256, 0, stream>>>(dst, E, degi, rank,
                                              W1, W2, W1f, W2f, lb, CB);
    scan_lb_kernel<<<SB, 256, 0, stream>>>(degi, N, lb, offs, dinv);
    fillgemm_kernel<<<FB + GB, 256, 0, stream>>>(x, W1f, h1, N, src, dst, E,
                                                 offs, rank, dinv, csr);
    aggmm_kernel<<<(N + 15) / 16, 256, 0, stream>>>(h1, offs, csr, dinv, b1, W2f, h2, N);
    aggout_kernel<<<(N + 3) / 4, 256, 0, stream>>>(h2, offs, csr, dinv, b2, out, N);
}